// Round 3
// baseline (94.869 us; speedup 1.0000x reference)
//
#include <hip/hip_runtime.h>
#include <hip/hip_bf16.h>

#define BB 128
#define FF 12288
#define HH 2048
#define TAU_F 0.1f
#define THR_F 1e-3f
#define NKG (FF / 8)          // 1536 k-groups of 8
#define BH (BB * HH)          // 262144

typedef __attribute__((ext_vector_type(4))) float f32x4;
typedef __attribute__((ext_vector_type(8))) short s16x8;
typedef __attribute__((ext_vector_type(8))) unsigned short u16x8;

#define AS1 __attribute__((address_space(1)))
#define AS3 __attribute__((address_space(3)))

// Round-to-nearest-even bf16 split: v ~= hi + lo with both bf16.
__device__ __forceinline__ void bsplit(float v, unsigned short& h, unsigned short& l) {
    unsigned int u  = __float_as_uint(v);
    unsigned int rh = (u + 0x7fffu + ((u >> 16) & 1u)) >> 16;
    float hf = __uint_as_float(rh << 16);
    float lf = v - hf;
    unsigned int ul = __float_as_uint(lf);
    unsigned int rl = (ul + 0x7fffu + ((ul >> 16) & 1u)) >> 16;
    h = (unsigned short)rh;
    l = (unsigned short)rl;
}

// ---------------------------------------------------------------------------
// x0 == 0 detector (deterministic).
__global__ void zdetect_kernel(const float4* __restrict__ x0, int n4,
                               int* __restrict__ flag) {
    int i = blockIdx.x * blockDim.x + threadIdx.x;
    bool nz = false;
    for (; i < n4; i += gridDim.x * blockDim.x) {
        float4 v = x0[i];
        nz |= (v.x != 0.f) | (v.y != 0.f) | (v.z != 0.f) | (v.w != 0.f);
    }
    if (nz) atomicOr(flag, 1);
}

// ---------------------------------------------------------------------------
// Pre-split x (and x0 if nonzero) into packed bf16 hi/lo, fragment-order
// layout: A*[z][kg][m][8] (16B per (kg,m) chunk) -> enables global_load_lds.
__global__ __launch_bounds__(256) void presplit_kernel(
    const float* __restrict__ x, const float* __restrict__ x0,
    unsigned short* __restrict__ Ah, unsigned short* __restrict__ Al,
    const int* __restrict__ flag) {
    const int z = blockIdx.y;
    if (z == 1 && *flag == 0) return;
    const float* __restrict__ X = z ? x0 : x;
    unsigned short* AH = Ah + (size_t)z * NKG * BB * 8;
    unsigned short* AL = Al + (size_t)z * NKG * BB * 8;
    const int t = threadIdx.x;
    const int kg = blockIdx.x * 8 + (t & 7);
#pragma unroll
    for (int r = 0; r < 4; ++r) {
        const int m = (t >> 3) + r * 32;
        const float* src = X + (size_t)m * FF + kg * 8;
        u16x8 hv, lv;
#pragma unroll
        for (int j = 0; j < 8; ++j) {
            unsigned short h, lo;
            bsplit(src[j], h, lo);
            hv[j] = h; lv[j] = lo;
        }
        const size_t o = ((size_t)kg * BB + m) * 8;
        *(u16x8*)(AH + o) = hv;
        *(u16x8*)(AL + o) = lv;
    }
}

// ---------------------------------------------------------------------------
// Split-precision MFMA GEMM partials: P[z*SK+kc] = X_z[:, kchunk] @ W1[kchunk, :].
// Tile 128x64, BK=32, double-buffered LDS (2 x 24 KB), splitK across blocks.
__global__ __launch_bounds__(256, 3) void mfma_gemm_kernel(
    const unsigned short* __restrict__ Ah, const unsigned short* __restrict__ Al,
    const float* __restrict__ W1, float* __restrict__ P,
    const int* __restrict__ nzflag, int SK, int KC, int NIT) {
    const int z = blockIdx.y;
    if (z == 1 && *nzflag == 0) return;

    // XCD-aware bijective swizzle (gridDim.x always % 8 == 0 here).
    const int nwg = gridDim.x;
    const int bx  = blockIdx.x;
    const int wg  = (bx & 7) * (nwg >> 3) + (bx >> 3);
    const int ct  = wg & 31;   // column tile (64 cols)
    const int kc  = wg >> 5;   // split-K chunk

    const int t   = threadIdx.x;
    const int w   = t >> 6;    // wave 0..3
    const int l   = t & 63;
    const int kgl = l >> 4;    // frag k-group 0..3
    const int li  = l & 15;

    __shared__ unsigned short lds[2][12288];

    const size_t zoffA = (size_t)z * NKG * BB * 8;
    const unsigned short* APH = Ah + zoffA;
    const unsigned short* APL = Al + zoffA;

    f32x4 acc[2][4];
#pragma unroll
    for (int mt = 0; mt < 2; ++mt)
#pragma unroll
        for (int nt = 0; nt < 4; ++nt) acc[mt][nt] = (f32x4)0.f;

    const int kbase = kc * KC;
    const int bkg = t >> 6;    // B staging: k-subgroup of 8
    const int bn  = t & 63;    // B staging: column within tile

    auto stageB_load = [&](int it, float* v) {
        const float* src = W1 + (size_t)(kbase + it * 32 + bkg * 8) * HH + ct * 64 + bn;
#pragma unroll
        for (int j = 0; j < 8; ++j) v[j] = src[(size_t)j * HH];
    };
    auto stageB_write = [&](int buf, const float* v) {
        u16x8 hv, lv;
#pragma unroll
        for (int j = 0; j < 8; ++j) {
            unsigned short h, lo;
            bsplit(v[j], h, lo);
            hv[j] = h; lv[j] = lo;
        }
        unsigned short* d = &lds[buf][(bkg * 64 + bn) * 8];
        *(u16x8*)(d + 8192)  = hv;
        *(u16x8*)(d + 10240) = lv;
    };
    auto stageA = [&](int it, int buf) {
        const int kg0 = (kbase + it * 32) >> 3;
#pragma unroll
        for (int s = 0; s < 4; ++s) {
            const int slot = w * 4 + s;      // 16 slots: 8 hi then 8 lo
            const int isLo = slot >> 3;
            const int sl   = slot & 7;
            const int kgq  = sl >> 1;
            const int mh   = sl & 1;
            const unsigned short* src = (isLo ? APL : APH)
                + ((size_t)(kg0 + kgq) * BB + mh * 64 + l) * 8;
            unsigned short* dst = &lds[buf][isLo * 4096 + (kgq * 128 + mh * 64) * 8];
            __builtin_amdgcn_global_load_lds((const AS1 void*)src, (AS3 void*)dst, 16, 0, 0);
        }
    };
    auto compute = [&](int buf) {
        const unsigned short* L = lds[buf];
        s16x8 fah[2], fal[2], fbh[4], fbl[4];
#pragma unroll
        for (int mt = 0; mt < 2; ++mt) {
            const int mo = (kgl * 128 + w * 32 + mt * 16 + li) * 8;
            fah[mt] = *(const s16x8*)&L[mo];
            fal[mt] = *(const s16x8*)&L[4096 + mo];
        }
#pragma unroll
        for (int nt = 0; nt < 4; ++nt) {
            const int no = (kgl * 64 + nt * 16 + li) * 8;
            fbh[nt] = *(const s16x8*)&L[8192 + no];
            fbl[nt] = *(const s16x8*)&L[10240 + no];
        }
#pragma unroll
        for (int mt = 0; mt < 2; ++mt)
#pragma unroll
            for (int nt = 0; nt < 4; ++nt) {
                acc[mt][nt] = __builtin_amdgcn_mfma_f32_16x16x32_bf16(fah[mt], fbh[nt], acc[mt][nt], 0, 0, 0);
                acc[mt][nt] = __builtin_amdgcn_mfma_f32_16x16x32_bf16(fah[mt], fbl[nt], acc[mt][nt], 0, 0, 0);
                acc[mt][nt] = __builtin_amdgcn_mfma_f32_16x16x32_bf16(fal[mt], fbh[nt], acc[mt][nt], 0, 0, 0);
            }
    };

    // Prologue: stage iter 0 into buffer 0.
    float bv[8];
    stageB_load(0, bv);
    stageA(0, 0);
    stageB_write(0, bv);
    __syncthreads();

    for (int it = 0; it < NIT; ++it) {
        const int cur = it & 1;
        const bool more = (it + 1 < NIT);
        float bnx[8];
        if (more) { stageB_load(it + 1, bnx); stageA(it + 1, cur ^ 1); }
        compute(cur);
        if (more) stageB_write(cur ^ 1, bnx);
        __syncthreads();
    }

    float* dst = P + (size_t)(z * SK + kc) * BH;
    const int r0 = w * 32 + (l >> 4) * 4;
    const int c0 = ct * 64 + li;
#pragma unroll
    for (int mt = 0; mt < 2; ++mt)
#pragma unroll
        for (int nt = 0; nt < 4; ++nt)
#pragma unroll
            for (int r = 0; r < 4; ++r)
                dst[(size_t)(r0 + mt * 16 + r) * HH + c0 + nt * 16] = acc[mt][nt][r];
}

// ---------------------------------------------------------------------------
// Legacy fp32 fallback GEMM (only if ws is tiny). SK=1 P layout.
__global__ __launch_bounds__(256) void legacy_gemm_kernel(
    const float* __restrict__ x, const float* __restrict__ x0,
    const float* __restrict__ W1, float* __restrict__ P,
    const int* __restrict__ nzflag) {
    const int ct = blockIdx.x, z = blockIdx.z, t = threadIdx.x;
    const int cg = t & 7, rg = t >> 3;
    const int r0 = rg * 4, cc = ct * 64 + cg * 8;
    float acc[4][8];
#pragma unroll
    for (int i = 0; i < 4; ++i)
#pragma unroll
        for (int n = 0; n < 8; ++n) acc[i][n] = 0.f;
    const float* __restrict__ X = z ? x0 : x;
    const bool skip = (z == 1) && (*nzflag == 0);
    if (!skip) {
        for (int k = 0; k < FF; k += 4) {
            float xr[4][4];
#pragma unroll
            for (int i = 0; i < 4; ++i) {
                float4 v = *(const float4*)(X + (size_t)(r0 + i) * FF + k);
                xr[i][0] = v.x; xr[i][1] = v.y; xr[i][2] = v.z; xr[i][3] = v.w;
            }
            float wr[4][8];
#pragma unroll
            for (int j = 0; j < 4; ++j) {
                float4 a = *(const float4*)(W1 + (size_t)(k + j) * HH + cc);
                float4 b = *(const float4*)(W1 + (size_t)(k + j) * HH + cc + 4);
                wr[j][0] = a.x; wr[j][1] = a.y; wr[j][2] = a.z; wr[j][3] = a.w;
                wr[j][4] = b.x; wr[j][5] = b.y; wr[j][6] = b.z; wr[j][7] = b.w;
            }
#pragma unroll
            for (int j = 0; j < 4; ++j)
#pragma unroll
                for (int i = 0; i < 4; ++i)
#pragma unroll
                    for (int n = 0; n < 8; ++n)
                        acc[i][n] = fmaf(xr[i][j], wr[j][n], acc[i][n]);
        }
    }
    float* Pp = P + (size_t)z * BH;
#pragma unroll
    for (int i = 0; i < 4; ++i) {
        float4 o0, o1;
        o0.x = acc[i][0]; o0.y = acc[i][1]; o0.z = acc[i][2]; o0.w = acc[i][3];
        o1.x = acc[i][4]; o1.y = acc[i][5]; o1.z = acc[i][6]; o1.w = acc[i][7];
        *(float4*)(Pp + (size_t)(r0 + i) * HH + cc) = o0;
        *(float4*)(Pp + (size_t)(r0 + i) * HH + cc + 4) = o1;
    }
}

// ---------------------------------------------------------------------------
// Fused: fixed-order split-K reduction + bisection + output write.
// One block (256 threads) per sample b. When x0 == 0 (flag clear), uses
// relu(c*u) = c*relu(u): f(c) = c*S - tau -> single reduction, scalar loop.
__global__ __launch_bounds__(256) void bisect_write_kernel(
    const float* __restrict__ P, const float* __restrict__ w2,
    const float* __restrict__ x, const float* __restrict__ x0,
    const int* __restrict__ flag, float* __restrict__ out, int SK) {
    const int b = blockIdx.x;
    const int t = threadIdx.x;
    const int w = t >> 6;
    const int lane = t & 63;
    __shared__ float red[4];
    const bool nz = (*flag != 0);

    float u1[8], wv[8];
#pragma unroll
    for (int j = 0; j < 8; ++j) {
        const int h = t + 256 * j;
        float s = 0.f;
        for (int kc = 0; kc < SK; ++kc)          // fixed order: deterministic
            s += P[(size_t)kc * BH + (size_t)b * HH + h];
        u1[j] = s;
        wv[j] = w2[h];
    }

    auto blockReduce = [&](float v) -> float {
#pragma unroll
        for (int off = 32; off > 0; off >>= 1) v += __shfl_xor(v, off);
        if (lane == 0) red[w] = v;
        __syncthreads();
        const float s = (red[0] + red[1]) + (red[2] + red[3]);
        __syncthreads();
        return s;
    };

    float c = 1.f;
    bool done = false;
    if (!nz) {
        // Linear path: f(c) = c*S - tau.
        float p = 0.f;
#pragma unroll
        for (int j = 0; j < 8; ++j) p = fmaf(fmaxf(u1[j], 0.f), wv[j], p);
        const float S = blockReduce(p);
        const float f1 = S - TAU_F;
        const bool inside = (f1 <= 0.f);
        float a = 0.f, bh = 1.f;
        done = inside;
        for (int it = 0; it < 30; ++it) {
            const float cm = 0.5f * (a + bh);
            const float v = cm * S - TAU_F;
            const bool upd  = !done;
            const bool hit  = upd && (v >= -THR_F) && (v < 0.f);
            const bool go_a = upd && (v < 0.f) && !hit;
            const bool go_b = upd && (v >= 0.f);
            a  = go_a ? cm : a;
            bh = go_b ? cm : bh;
            c  = upd  ? cm : c;
            done = done || hit;
        }
        c = inside ? 1.f : c;
    } else {
        float u0[8], dd[8];
#pragma unroll
        for (int j = 0; j < 8; ++j) {
            const int h = t + 256 * j;
            float s = 0.f;
            for (int kc = 0; kc < SK; ++kc)
                s += P[(size_t)(SK + kc) * BH + (size_t)b * HH + h];
            u0[j] = s;
            dd[j] = u1[j] - s;
        }
        auto feval = [&](float cc) -> float {
            float p = 0.f;
#pragma unroll
            for (int j = 0; j < 8; ++j)
                p = fmaf(fmaxf(fmaf(cc, dd[j], u0[j]), 0.f), wv[j], p);
            return blockReduce(p) - TAU_F;
        };
        const float f1 = feval(1.f);
        const bool inside = (f1 <= 0.f);
        float a = 0.f, bh = 1.f;
        done = inside;
        for (int it = 0; it < 30; ++it) {
            const float cm = 0.5f * (a + bh);
            const float v = feval(cm);
            const bool upd  = !done;
            const bool hit  = upd && (v >= -THR_F) && (v < 0.f);
            const bool go_a = upd && (v < 0.f) && !hit;
            const bool go_b = upd && (v >= 0.f);
            a  = go_a ? cm : a;
            bh = go_b ? cm : bh;
            c  = upd  ? cm : c;
            done = done || hit;
        }
        c = inside ? 1.f : c;
    }

    // Write output row b (uniform branches across block).
    const float nanv = __int_as_float(0x7fc00000);
    const float4* xr  = (const float4*)(x  + (size_t)b * FF);
    const float4* x0r = (const float4*)(x0 + (size_t)b * FF);
    float4* orow = (float4*)(out + (size_t)b * FF);
    if (!done) {
        float4 o; o.x = o.y = o.z = o.w = nanv;
#pragma unroll
        for (int k2 = 0; k2 < 12; ++k2) orow[t + 256 * k2] = o;
    } else if (!nz) {
#pragma unroll
        for (int k2 = 0; k2 < 12; ++k2) {
            const int i = t + 256 * k2;
            float4 xv = xr[i], o;
            o.x = c * xv.x; o.y = c * xv.y; o.z = c * xv.z; o.w = c * xv.w;
            orow[i] = o;
        }
    } else {
#pragma unroll
        for (int k2 = 0; k2 < 12; ++k2) {
            const int i = t + 256 * k2;
            float4 xv = xr[i], zv = x0r[i], o;
            o.x = fmaf(c, xv.x - zv.x, zv.x);
            o.y = fmaf(c, xv.y - zv.y, zv.y);
            o.z = fmaf(c, xv.z - zv.z, zv.z);
            o.w = fmaf(c, xv.w - zv.w, zv.w);
            orow[i] = o;
        }
    }
}

// ---------------------------------------------------------------------------
extern "C" void kernel_launch(void* const* d_in, const int* in_sizes, int n_in,
                              void* d_out, int out_size, void* d_ws, size_t ws_size,
                              hipStream_t stream) {
    const float* x0 = (const float*)d_in[0];
    const float* x  = (const float*)d_in[1];
    const float* W1 = (const float*)d_in[2];
    const float* w2 = (const float*)d_in[3];
    float* out = (float*)d_out;
    char* ws = (char*)d_ws;

    // ws layout: Ah | Al | flag | P[2*SK][B][H]
    const size_t szA   = (size_t)2 * NKG * BB * 8 * sizeof(unsigned short); // 6291456
    const size_t offAl = szA;
    const size_t offFl = 2 * szA;
    const size_t offP  = 2 * szA + 256;

    int SK = 0;
    const int cand[5] = {24, 12, 6, 3, 1};
    for (int i = 0; i < 5; ++i) {
        const size_t need = offP + (size_t)2 * cand[i] * BH * sizeof(float);
        if (ws_size >= need) { SK = cand[i]; break; }
    }

    if (SK > 0) {
        unsigned short* Ah = (unsigned short*)ws;
        unsigned short* Al = (unsigned short*)(ws + offAl);
        int*   flag  = (int*)(ws + offFl);
        float* P     = (float*)(ws + offP);
        const int KC = FF / SK, NIT = KC / 32;

        hipMemsetAsync(flag, 0, sizeof(int), stream);
        zdetect_kernel<<<256, 256, 0, stream>>>((const float4*)x0, BB * FF / 4, flag);
        presplit_kernel<<<dim3(NKG / 8, 2), 256, 0, stream>>>(x, x0, Ah, Al, flag);
        mfma_gemm_kernel<<<dim3(32 * SK, 2), 256, 0, stream>>>(Ah, Al, W1, P, flag, SK, KC, NIT);
        bisect_write_kernel<<<BB, 256, 0, stream>>>(P, w2, x, x0, flag, out, SK);
    } else {
        // Low-memory fallback: fp32 VALU GEMM, SK=1 layout.
        float* P    = (float*)ws;
        int*   flag = (int*)(ws + (size_t)2 * BH * sizeof(float));
        hipMemsetAsync(flag, 0, sizeof(int), stream);
        zdetect_kernel<<<256, 256, 0, stream>>>((const float4*)x0, BB * FF / 4, flag);
        legacy_gemm_kernel<<<dim3(32, 1, 2), 256, 0, stream>>>(x, x0, W1, P, flag);
        bisect_write_kernel<<<BB, 256, 0, stream>>>(P, w2, x, x0, flag, out, 1);
    }
}

// Round 4
// 55.947 us; speedup vs baseline: 1.6957x; 1.6957x over previous
//
#include <hip/hip_runtime.h>
#include <hip/hip_bf16.h>

#define BB 128
#define FF 12288
#define HH 2048
#define TAU_F 0.1f
#define THR_F 1e-3f
#define NKG (FF / 8)          // 1536 k-groups of 8
#define BH (BB * HH)          // 262144

typedef __attribute__((ext_vector_type(4))) float f32x4;
typedef __attribute__((ext_vector_type(8))) short s16x8;
typedef __attribute__((ext_vector_type(8))) unsigned short u16x8;

#define AS1 __attribute__((address_space(1)))
#define AS3 __attribute__((address_space(3)))

// Round-to-nearest-even bf16 split: v ~= hi + lo with both bf16.
__device__ __forceinline__ void bsplit(float v, unsigned short& h, unsigned short& l) {
    unsigned int u  = __float_as_uint(v);
    unsigned int rh = (u + 0x7fffu + ((u >> 16) & 1u)) >> 16;
    float hf = __uint_as_float(rh << 16);
    float lf = v - hf;
    unsigned int ul = __float_as_uint(lf);
    unsigned int rl = (ul + 0x7fffu + ((ul >> 16) & 1u)) >> 16;
    h = (unsigned short)rh;
    l = (unsigned short)rl;
}

// ---------------------------------------------------------------------------
// x0 == 0 detector (deterministic).
__global__ void zdetect_kernel(const float4* __restrict__ x0, int n4,
                               int* __restrict__ flag) {
    int i = blockIdx.x * blockDim.x + threadIdx.x;
    bool nz = false;
    for (; i < n4; i += gridDim.x * blockDim.x) {
        float4 v = x0[i];
        nz |= (v.x != 0.f) | (v.y != 0.f) | (v.z != 0.f) | (v.w != 0.f);
    }
    if (nz) atomicOr(flag, 1);
}

// ---------------------------------------------------------------------------
// Pre-split x (and x0 if nonzero) into packed bf16 hi/lo, fragment-order
// layout: A*[z][kg][m][8] (16B per (kg,m) chunk) -> enables global_load_lds.
__global__ __launch_bounds__(256) void presplit_kernel(
    const float* __restrict__ x, const float* __restrict__ x0,
    unsigned short* __restrict__ Ah, unsigned short* __restrict__ Al,
    const int* __restrict__ flag) {
    const int z = blockIdx.y;
    if (z == 1 && *flag == 0) return;
    const float* __restrict__ X = z ? x0 : x;
    unsigned short* AH = Ah + (size_t)z * NKG * BB * 8;
    unsigned short* AL = Al + (size_t)z * NKG * BB * 8;
    const int t = threadIdx.x;
    const int kg = blockIdx.x * 8 + (t & 7);
#pragma unroll
    for (int r = 0; r < 4; ++r) {
        const int m = (t >> 3) + r * 32;
        const float* src = X + (size_t)m * FF + kg * 8;
        u16x8 hv, lv;
#pragma unroll
        for (int j = 0; j < 8; ++j) {
            unsigned short h, lo;
            bsplit(src[j], h, lo);
            hv[j] = h; lv[j] = lo;
        }
        const size_t o = ((size_t)kg * BB + m) * 8;
        *(u16x8*)(AH + o) = hv;
        *(u16x8*)(AL + o) = lv;
    }
}

// ---------------------------------------------------------------------------
// Split-precision MFMA GEMM partials: P[z*SK+kc] = X_z[:, kchunk] @ W1[kchunk, :].
// Tile 128x64, BK=32, double-buffered LDS (2 x 24 KB), splitK across blocks.
__global__ __launch_bounds__(256, 3) void mfma_gemm_kernel(
    const unsigned short* __restrict__ Ah, const unsigned short* __restrict__ Al,
    const float* __restrict__ W1, float* __restrict__ P,
    const int* __restrict__ nzflag, int SK, int KC, int NIT) {
    const int z = blockIdx.y;
    if (z == 1 && *nzflag == 0) return;

    // XCD-aware bijective swizzle (gridDim.x always % 8 == 0 here).
    const int nwg = gridDim.x;
    const int bx  = blockIdx.x;
    const int wg  = (bx & 7) * (nwg >> 3) + (bx >> 3);
    const int ct  = wg & 31;   // column tile (64 cols)
    const int kc  = wg >> 5;   // split-K chunk

    const int t   = threadIdx.x;
    const int w   = t >> 6;    // wave 0..3
    const int l   = t & 63;
    const int kgl = l >> 4;    // frag k-group 0..3
    const int li  = l & 15;

    __shared__ unsigned short lds[2][12288];

    const size_t zoffA = (size_t)z * NKG * BB * 8;
    const unsigned short* APH = Ah + zoffA;
    const unsigned short* APL = Al + zoffA;

    f32x4 acc[2][4];
#pragma unroll
    for (int mt = 0; mt < 2; ++mt)
#pragma unroll
        for (int nt = 0; nt < 4; ++nt) acc[mt][nt] = (f32x4)0.f;

    const int kbase = kc * KC;
    const int bkg = t >> 6;    // B staging: k-subgroup of 8
    const int bn  = t & 63;    // B staging: column within tile

    auto stageB_load = [&](int it, float* v) {
        const float* src = W1 + (size_t)(kbase + it * 32 + bkg * 8) * HH + ct * 64 + bn;
#pragma unroll
        for (int j = 0; j < 8; ++j) v[j] = src[(size_t)j * HH];
    };
    auto stageB_write = [&](int buf, const float* v) {
        u16x8 hv, lv;
#pragma unroll
        for (int j = 0; j < 8; ++j) {
            unsigned short h, lo;
            bsplit(v[j], h, lo);
            hv[j] = h; lv[j] = lo;
        }
        unsigned short* d = &lds[buf][(bkg * 64 + bn) * 8];
        *(u16x8*)(d + 8192)  = hv;
        *(u16x8*)(d + 10240) = lv;
    };
    auto stageA = [&](int it, int buf) {
        const int kg0 = (kbase + it * 32) >> 3;
#pragma unroll
        for (int s = 0; s < 4; ++s) {
            const int slot = w * 4 + s;      // 16 slots: 8 hi then 8 lo
            const int isLo = slot >> 3;
            const int sl   = slot & 7;
            const int kgq  = sl >> 1;
            const int mh   = sl & 1;
            const unsigned short* src = (isLo ? APL : APH)
                + ((size_t)(kg0 + kgq) * BB + mh * 64 + l) * 8;
            unsigned short* dst = &lds[buf][isLo * 4096 + (kgq * 128 + mh * 64) * 8];
            __builtin_amdgcn_global_load_lds((const AS1 void*)src, (AS3 void*)dst, 16, 0, 0);
        }
    };
    auto compute = [&](int buf) {
        const unsigned short* L = lds[buf];
        s16x8 fah[2], fal[2], fbh[4], fbl[4];
#pragma unroll
        for (int mt = 0; mt < 2; ++mt) {
            const int mo = (kgl * 128 + w * 32 + mt * 16 + li) * 8;
            fah[mt] = *(const s16x8*)&L[mo];
            fal[mt] = *(const s16x8*)&L[4096 + mo];
        }
#pragma unroll
        for (int nt = 0; nt < 4; ++nt) {
            const int no = (kgl * 64 + nt * 16 + li) * 8;
            fbh[nt] = *(const s16x8*)&L[8192 + no];
            fbl[nt] = *(const s16x8*)&L[10240 + no];
        }
#pragma unroll
        for (int mt = 0; mt < 2; ++mt)
#pragma unroll
            for (int nt = 0; nt < 4; ++nt) {
                acc[mt][nt] = __builtin_amdgcn_mfma_f32_16x16x32_bf16(fah[mt], fbh[nt], acc[mt][nt], 0, 0, 0);
                acc[mt][nt] = __builtin_amdgcn_mfma_f32_16x16x32_bf16(fah[mt], fbl[nt], acc[mt][nt], 0, 0, 0);
                acc[mt][nt] = __builtin_amdgcn_mfma_f32_16x16x32_bf16(fal[mt], fbh[nt], acc[mt][nt], 0, 0, 0);
            }
    };

    // Prologue: stage iter 0 into buffer 0.
    float bv[8];
    stageB_load(0, bv);
    stageA(0, 0);
    stageB_write(0, bv);
    __syncthreads();

    for (int it = 0; it < NIT; ++it) {
        const int cur = it & 1;
        const bool more = (it + 1 < NIT);
        float bnx[8];
        if (more) { stageB_load(it + 1, bnx); stageA(it + 1, cur ^ 1); }
        compute(cur);
        if (more) stageB_write(cur ^ 1, bnx);
        __syncthreads();
    }

    float* dst = P + (size_t)(z * SK + kc) * BH;
    const int r0 = w * 32 + (l >> 4) * 4;
    const int c0 = ct * 64 + li;
#pragma unroll
    for (int mt = 0; mt < 2; ++mt)
#pragma unroll
        for (int nt = 0; nt < 4; ++nt)
#pragma unroll
            for (int r = 0; r < 4; ++r)
                dst[(size_t)(r0 + mt * 16 + r) * HH + c0 + nt * 16] = acc[mt][nt][r];
}

// ---------------------------------------------------------------------------
// Wide deterministic fixed-order split-K reduction: U[z] = sum_kc P[z][kc].
// float4 per thread, 512 blocks -> full HBM parallelism.
__global__ __launch_bounds__(256) void reduce_kernel(
    const float4* __restrict__ P4, float4* __restrict__ U4,
    const int* __restrict__ flag, int SK) {
    const int z = blockIdx.y;
    if (z == 1 && *flag == 0) return;   // bisect_write won't read U[1] then
    const size_t idx = (size_t)blockIdx.x * 256 + threadIdx.x;   // over BH/4
    const size_t zo = (size_t)z * SK * (BH / 4);
    float4 s = {0.f, 0.f, 0.f, 0.f};
    for (int kc = 0; kc < SK; ++kc) {   // fixed order: deterministic
        float4 v = P4[zo + (size_t)kc * (BH / 4) + idx];
        s.x += v.x; s.y += v.y; s.z += v.z; s.w += v.w;
    }
    U4[(size_t)z * (BH / 4) + idx] = s;
}

// ---------------------------------------------------------------------------
// Legacy fp32 fallback GEMM (only if ws is tiny). Writes U layout directly.
__global__ __launch_bounds__(256) void legacy_gemm_kernel(
    const float* __restrict__ x, const float* __restrict__ x0,
    const float* __restrict__ W1, float* __restrict__ P,
    const int* __restrict__ nzflag) {
    const int ct = blockIdx.x, z = blockIdx.z, t = threadIdx.x;
    const int cg = t & 7, rg = t >> 3;
    const int r0 = rg * 4, cc = ct * 64 + cg * 8;
    float acc[4][8];
#pragma unroll
    for (int i = 0; i < 4; ++i)
#pragma unroll
        for (int n = 0; n < 8; ++n) acc[i][n] = 0.f;
    const float* __restrict__ X = z ? x0 : x;
    const bool skip = (z == 1) && (*nzflag == 0);
    if (!skip) {
        for (int k = 0; k < FF; k += 4) {
            float xr[4][4];
#pragma unroll
            for (int i = 0; i < 4; ++i) {
                float4 v = *(const float4*)(X + (size_t)(r0 + i) * FF + k);
                xr[i][0] = v.x; xr[i][1] = v.y; xr[i][2] = v.z; xr[i][3] = v.w;
            }
            float wr[4][8];
#pragma unroll
            for (int j = 0; j < 4; ++j) {
                float4 a = *(const float4*)(W1 + (size_t)(k + j) * HH + cc);
                float4 b = *(const float4*)(W1 + (size_t)(k + j) * HH + cc + 4);
                wr[j][0] = a.x; wr[j][1] = a.y; wr[j][2] = a.z; wr[j][3] = a.w;
                wr[j][4] = b.x; wr[j][5] = b.y; wr[j][6] = b.z; wr[j][7] = b.w;
            }
#pragma unroll
            for (int j = 0; j < 4; ++j)
#pragma unroll
                for (int i = 0; i < 4; ++i)
#pragma unroll
                    for (int n = 0; n < 8; ++n)
                        acc[i][n] = fmaf(xr[i][j], wr[j][n], acc[i][n]);
        }
    }
    float* Pp = P + (size_t)z * BH;
#pragma unroll
    for (int i = 0; i < 4; ++i) {
        float4 o0, o1;
        o0.x = acc[i][0]; o0.y = acc[i][1]; o0.z = acc[i][2]; o0.w = acc[i][3];
        o1.x = acc[i][4]; o1.y = acc[i][5]; o1.z = acc[i][6]; o1.w = acc[i][7];
        *(float4*)(Pp + (size_t)(r0 + i) * HH + cc) = o0;
        *(float4*)(Pp + (size_t)(r0 + i) * HH + cc + 4) = o1;
    }
}

// ---------------------------------------------------------------------------
// Fused bisection + output write, reading the small U (2 MB, L2/L3-hot).
// One block (256 threads) per sample b. When x0 == 0 (flag clear), uses
// relu(c*u) = c*relu(u): f(c) = c*S - tau -> single reduction, scalar loop.
__global__ __launch_bounds__(256) void bisect_write_kernel(
    const float* __restrict__ U, const float* __restrict__ w2,
    const float* __restrict__ x, const float* __restrict__ x0,
    const int* __restrict__ flag, float* __restrict__ out) {
    const int b = blockIdx.x;
    const int t = threadIdx.x;
    const int w = t >> 6;
    const int lane = t & 63;
    __shared__ float red[4];
    const bool nz = (*flag != 0);

    float u1[8], wv[8];
#pragma unroll
    for (int j = 0; j < 8; ++j) {
        const int h = t + 256 * j;
        u1[j] = U[(size_t)b * HH + h];
        wv[j] = w2[h];
    }

    auto blockReduce = [&](float v) -> float {
#pragma unroll
        for (int off = 32; off > 0; off >>= 1) v += __shfl_xor(v, off);
        if (lane == 0) red[w] = v;
        __syncthreads();
        const float s = (red[0] + red[1]) + (red[2] + red[3]);
        __syncthreads();
        return s;
    };

    float c = 1.f;
    bool done = false;
    if (!nz) {
        // Linear path: f(c) = c*S - tau.
        float p = 0.f;
#pragma unroll
        for (int j = 0; j < 8; ++j) p = fmaf(fmaxf(u1[j], 0.f), wv[j], p);
        const float S = blockReduce(p);
        const float f1 = S - TAU_F;
        const bool inside = (f1 <= 0.f);
        float a = 0.f, bh = 1.f;
        done = inside;
        for (int it = 0; it < 30; ++it) {
            const float cm = 0.5f * (a + bh);
            const float v = cm * S - TAU_F;
            const bool upd  = !done;
            const bool hit  = upd && (v >= -THR_F) && (v < 0.f);
            const bool go_a = upd && (v < 0.f) && !hit;
            const bool go_b = upd && (v >= 0.f);
            a  = go_a ? cm : a;
            bh = go_b ? cm : bh;
            c  = upd  ? cm : c;
            done = done || hit;
        }
        c = inside ? 1.f : c;
    } else {
        float u0[8], dd[8];
#pragma unroll
        for (int j = 0; j < 8; ++j) {
            const int h = t + 256 * j;
            const float s0 = U[BH + (size_t)b * HH + h];
            u0[j] = s0;
            dd[j] = u1[j] - s0;
        }
        auto feval = [&](float cc) -> float {
            float p = 0.f;
#pragma unroll
            for (int j = 0; j < 8; ++j)
                p = fmaf(fmaxf(fmaf(cc, dd[j], u0[j]), 0.f), wv[j], p);
            return blockReduce(p) - TAU_F;
        };
        const float f1 = feval(1.f);
        const bool inside = (f1 <= 0.f);
        float a = 0.f, bh = 1.f;
        done = inside;
        for (int it = 0; it < 30; ++it) {
            const float cm = 0.5f * (a + bh);
            const float v = feval(cm);
            const bool upd  = !done;
            const bool hit  = upd && (v >= -THR_F) && (v < 0.f);
            const bool go_a = upd && (v < 0.f) && !hit;
            const bool go_b = upd && (v >= 0.f);
            a  = go_a ? cm : a;
            bh = go_b ? cm : bh;
            c  = upd  ? cm : c;
            done = done || hit;
        }
        c = inside ? 1.f : c;
    }

    // Write output row b (uniform branches across block).
    const float nanv = __int_as_float(0x7fc00000);
    const float4* xr  = (const float4*)(x  + (size_t)b * FF);
    const float4* x0r = (const float4*)(x0 + (size_t)b * FF);
    float4* orow = (float4*)(out + (size_t)b * FF);
    if (!done) {
        float4 o; o.x = o.y = o.z = o.w = nanv;
#pragma unroll
        for (int k2 = 0; k2 < 12; ++k2) orow[t + 256 * k2] = o;
    } else if (!nz) {
#pragma unroll
        for (int k2 = 0; k2 < 12; ++k2) {
            const int i = t + 256 * k2;
            float4 xv = xr[i], o;
            o.x = c * xv.x; o.y = c * xv.y; o.z = c * xv.z; o.w = c * xv.w;
            orow[i] = o;
        }
    } else {
#pragma unroll
        for (int k2 = 0; k2 < 12; ++k2) {
            const int i = t + 256 * k2;
            float4 xv = xr[i], zv = x0r[i], o;
            o.x = fmaf(c, xv.x - zv.x, zv.x);
            o.y = fmaf(c, xv.y - zv.y, zv.y);
            o.z = fmaf(c, xv.z - zv.z, zv.z);
            o.w = fmaf(c, xv.w - zv.w, zv.w);
            orow[i] = o;
        }
    }
}

// ---------------------------------------------------------------------------
extern "C" void kernel_launch(void* const* d_in, const int* in_sizes, int n_in,
                              void* d_out, int out_size, void* d_ws, size_t ws_size,
                              hipStream_t stream) {
    const float* x0 = (const float*)d_in[0];
    const float* x  = (const float*)d_in[1];
    const float* W1 = (const float*)d_in[2];
    const float* w2 = (const float*)d_in[3];
    float* out = (float*)d_out;
    char* ws = (char*)d_ws;

    // ws layout: Ah | Al | U[2][B][H] | flag | P[2*SK][B][H]
    const size_t szA   = (size_t)2 * NKG * BB * 8 * sizeof(unsigned short); // 6291456
    const size_t offAl = szA;
    const size_t offU  = 2 * szA;
    const size_t offFl = offU + (size_t)2 * BH * sizeof(float);
    const size_t offP  = offFl + 256;

    int SK = 0;
    const int cand[5] = {16, 8, 4, 2, 1};
    for (int i = 0; i < 5; ++i) {
        const size_t need = offP + (size_t)2 * cand[i] * BH * sizeof(float);
        if (ws_size >= need) { SK = cand[i]; break; }
    }

    if (SK > 0) {
        unsigned short* Ah = (unsigned short*)ws;
        unsigned short* Al = (unsigned short*)(ws + offAl);
        float* U     = (float*)(ws + offU);
        int*   flag  = (int*)(ws + offFl);
        float* P     = (float*)(ws + offP);
        const int KC = FF / SK, NIT = KC / 32;

        hipMemsetAsync(flag, 0, sizeof(int), stream);
        zdetect_kernel<<<512, 256, 0, stream>>>((const float4*)x0, BB * FF / 4, flag);
        presplit_kernel<<<dim3(NKG / 8, 2), 256, 0, stream>>>(x, x0, Ah, Al, flag);
        mfma_gemm_kernel<<<dim3(32 * SK, 2), 256, 0, stream>>>(Ah, Al, W1, P, flag, SK, KC, NIT);
        reduce_kernel<<<dim3(BH / 4 / 256, 2), 256, 0, stream>>>((const float4*)P, (float4*)U, flag, SK);
        bisect_write_kernel<<<BB, 256, 0, stream>>>(U, w2, x, x0, flag, out);
    } else {
        // Low-memory fallback: fp32 VALU GEMM straight into U layout.
        float* U    = (float*)ws;
        int*   flag = (int*)(ws + (size_t)2 * BH * sizeof(float));
        hipMemsetAsync(flag, 0, sizeof(int), stream);
        zdetect_kernel<<<512, 256, 0, stream>>>((const float4*)x0, BB * FF / 4, flag);
        legacy_gemm_kernel<<<dim3(32, 1, 2), 256, 0, stream>>>(x, x0, W1, U, flag);
        bisect_write_kernel<<<BB, 256, 0, stream>>>(U, w2, x, x0, flag, out);
    }
}

// Round 5
// 50.128 us; speedup vs baseline: 1.8925x; 1.1161x over previous
//
#include <hip/hip_runtime.h>
#include <hip/hip_bf16.h>

#define BB 128
#define FF 12288
#define HH 2048
#define TAU_F 0.1f
#define THR_F 1e-3f
#define NKG (FF / 8)          // 1536 k-groups of 8
#define BH (BB * HH)          // 262144
#define NFLAGS 192            // per-block x0-nonzero flags (written every call)

typedef __attribute__((ext_vector_type(4))) float f32x4;
typedef __attribute__((ext_vector_type(8))) short s16x8;
typedef __attribute__((ext_vector_type(8))) unsigned short u16x8;

#define AS1 __attribute__((address_space(1)))
#define AS3 __attribute__((address_space(3)))

// Round-to-nearest-even bf16 split: v ~= hi + lo with both bf16.
__device__ __forceinline__ void bsplit(float v, unsigned short& h, unsigned short& l) {
    unsigned int u  = __float_as_uint(v);
    unsigned int rh = (u + 0x7fffu + ((u >> 16) & 1u)) >> 16;
    float hf = __uint_as_float(rh << 16);
    float lf = v - hf;
    unsigned int ul = __float_as_uint(lf);
    unsigned int rl = (ul + 0x7fffu + ((ul >> 16) & 1u)) >> 16;
    h = (unsigned short)rh;
    l = (unsigned short)rl;
}

// Wave-uniform OR over the 192 flag ints (48 int4 loads across lanes 0..47).
__device__ __forceinline__ bool read_nz(const int* __restrict__ flags) {
    const int lane = threadIdx.x & 63;
    int v = 0;
    if (lane < NFLAGS / 4) {
        const int4 q = ((const int4*)flags)[lane];
        v = q.x | q.y | q.z | q.w;
    }
    return __any(v != 0);
}

// ---------------------------------------------------------------------------
// Pre-split x (z=0) and x0 (z=1) into packed bf16 hi/lo, fragment-order
// layout A*[z][kg][m][8]. z=1 additionally writes per-block nonzero flags
// (unconditional full overwrite of flags[] -> no init kernel needed).
__global__ __launch_bounds__(256) void presplit_kernel(
    const float* __restrict__ x, const float* __restrict__ x0,
    unsigned short* __restrict__ Ah, unsigned short* __restrict__ Al,
    int* __restrict__ flags) {
    const int z = blockIdx.y;
    const float* __restrict__ X = z ? x0 : x;
    unsigned short* AH = Ah + (size_t)z * NKG * BB * 8;
    unsigned short* AL = Al + (size_t)z * NKG * BB * 8;
    const int t = threadIdx.x;
    const int w = t >> 6, lane = t & 63;
    const int kg = blockIdx.x * 8 + (t & 7);
    __shared__ int snz[4];
    int tnz = 0;
#pragma unroll
    for (int r = 0; r < 4; ++r) {
        const int m = (t >> 3) + r * 32;
        const float* src = X + (size_t)m * FF + kg * 8;
        u16x8 hv, lv;
#pragma unroll
        for (int j = 0; j < 8; ++j) {
            const float v = src[j];
            tnz |= (v != 0.f);
            unsigned short h, lo;
            bsplit(v, h, lo);
            hv[j] = h; lv[j] = lo;
        }
        const size_t o = ((size_t)kg * BB + m) * 8;
        *(u16x8*)(AH + o) = hv;
        *(u16x8*)(AL + o) = lv;
    }
    if (z == 1) {
        const int wnz = __any(tnz != 0) ? 1 : 0;
        if (lane == 0) snz[w] = wnz;
        __syncthreads();
        if (t == 0) flags[blockIdx.x] = snz[0] | snz[1] | snz[2] | snz[3];
    }
}

// ---------------------------------------------------------------------------
// Split-precision MFMA GEMM partials: P[z*SK+kc] = X_z[:, kchunk] @ W1[kchunk, :].
// Tile 128x64, BK=32, double-buffered LDS (2 x 24 KB), splitK across blocks.
__global__ __launch_bounds__(256, 3) void mfma_gemm_kernel(
    const unsigned short* __restrict__ Ah, const unsigned short* __restrict__ Al,
    const float* __restrict__ W1, float* __restrict__ P,
    const int* __restrict__ flags, int SK, int KC, int NIT) {
    const int z = blockIdx.y;
    if (z == 1 && !read_nz(flags)) return;

    // XCD-aware bijective swizzle (gridDim.x always % 8 == 0 here).
    const int nwg = gridDim.x;
    const int bx  = blockIdx.x;
    const int wg  = (bx & 7) * (nwg >> 3) + (bx >> 3);
    const int ct  = wg & 31;   // column tile (64 cols)
    const int kc  = wg >> 5;   // split-K chunk

    const int t   = threadIdx.x;
    const int w   = t >> 6;    // wave 0..3
    const int l   = t & 63;
    const int kgl = l >> 4;    // frag k-group 0..3
    const int li  = l & 15;

    __shared__ unsigned short lds[2][12288];

    const size_t zoffA = (size_t)z * NKG * BB * 8;
    const unsigned short* APH = Ah + zoffA;
    const unsigned short* APL = Al + zoffA;

    f32x4 acc[2][4];
#pragma unroll
    for (int mt = 0; mt < 2; ++mt)
#pragma unroll
        for (int nt = 0; nt < 4; ++nt) acc[mt][nt] = (f32x4)0.f;

    const int kbase = kc * KC;
    const int bkg = t >> 6;    // B staging: k-subgroup of 8
    const int bn  = t & 63;    // B staging: column within tile

    auto stageB_load = [&](int it, float* v) {
        const float* src = W1 + (size_t)(kbase + it * 32 + bkg * 8) * HH + ct * 64 + bn;
#pragma unroll
        for (int j = 0; j < 8; ++j) v[j] = src[(size_t)j * HH];
    };
    auto stageB_write = [&](int buf, const float* v) {
        u16x8 hv, lv;
#pragma unroll
        for (int j = 0; j < 8; ++j) {
            unsigned short h, lo;
            bsplit(v[j], h, lo);
            hv[j] = h; lv[j] = lo;
        }
        unsigned short* d = &lds[buf][(bkg * 64 + bn) * 8];
        *(u16x8*)(d + 8192)  = hv;
        *(u16x8*)(d + 10240) = lv;
    };
    auto stageA = [&](int it, int buf) {
        const int kg0 = (kbase + it * 32) >> 3;
#pragma unroll
        for (int s = 0; s < 4; ++s) {
            const int slot = w * 4 + s;      // 16 slots: 8 hi then 8 lo
            const int isLo = slot >> 3;
            const int sl   = slot & 7;
            const int kgq  = sl >> 1;
            const int mh   = sl & 1;
            const unsigned short* src = (isLo ? APL : APH)
                + ((size_t)(kg0 + kgq) * BB + mh * 64 + l) * 8;
            unsigned short* dst = &lds[buf][isLo * 4096 + (kgq * 128 + mh * 64) * 8];
            __builtin_amdgcn_global_load_lds((const AS1 void*)src, (AS3 void*)dst, 16, 0, 0);
        }
    };
    auto compute = [&](int buf) {
        const unsigned short* L = lds[buf];
        s16x8 fah[2], fal[2], fbh[4], fbl[4];
#pragma unroll
        for (int mt = 0; mt < 2; ++mt) {
            const int mo = (kgl * 128 + w * 32 + mt * 16 + li) * 8;
            fah[mt] = *(const s16x8*)&L[mo];
            fal[mt] = *(const s16x8*)&L[4096 + mo];
        }
#pragma unroll
        for (int nt = 0; nt < 4; ++nt) {
            const int no = (kgl * 64 + nt * 16 + li) * 8;
            fbh[nt] = *(const s16x8*)&L[8192 + no];
            fbl[nt] = *(const s16x8*)&L[10240 + no];
        }
#pragma unroll
        for (int mt = 0; mt < 2; ++mt)
#pragma unroll
            for (int nt = 0; nt < 4; ++nt) {
                acc[mt][nt] = __builtin_amdgcn_mfma_f32_16x16x32_bf16(fah[mt], fbh[nt], acc[mt][nt], 0, 0, 0);
                acc[mt][nt] = __builtin_amdgcn_mfma_f32_16x16x32_bf16(fah[mt], fbl[nt], acc[mt][nt], 0, 0, 0);
                acc[mt][nt] = __builtin_amdgcn_mfma_f32_16x16x32_bf16(fal[mt], fbh[nt], acc[mt][nt], 0, 0, 0);
            }
    };

    // Prologue: stage iter 0 into buffer 0.
    float bv[8];
    stageB_load(0, bv);
    stageA(0, 0);
    stageB_write(0, bv);
    __syncthreads();

    for (int it = 0; it < NIT; ++it) {
        const int cur = it & 1;
        const bool more = (it + 1 < NIT);
        float bnx[8];
        if (more) { stageB_load(it + 1, bnx); stageA(it + 1, cur ^ 1); }
        compute(cur);
        if (more) stageB_write(cur ^ 1, bnx);
        __syncthreads();
    }

    float* dst = P + (size_t)(z * SK + kc) * BH;
    const int r0 = w * 32 + (l >> 4) * 4;
    const int c0 = ct * 64 + li;
#pragma unroll
    for (int mt = 0; mt < 2; ++mt)
#pragma unroll
        for (int nt = 0; nt < 4; ++nt)
#pragma unroll
            for (int r = 0; r < 4; ++r)
                dst[(size_t)(r0 + mt * 16 + r) * HH + c0 + nt * 16] = acc[mt][nt][r];
}

// ---------------------------------------------------------------------------
// x0 flags for the low-memory fallback path (no presplit there).
__global__ __launch_bounds__(256) void zflags_kernel(
    const float4* __restrict__ x0, int* __restrict__ flags) {
    const int t = threadIdx.x;
    const int w = t >> 6, lane = t & 63;
    __shared__ int snz[4];
    int tnz = 0;
    const int base = blockIdx.x * 2048 + t;   // 192 blocks * 2048 f4 = BB*FF/4
#pragma unroll
    for (int j = 0; j < 8; ++j) {
        float4 v = x0[base + 256 * j];
        tnz |= (v.x != 0.f) | (v.y != 0.f) | (v.z != 0.f) | (v.w != 0.f);
    }
    const int wnz = __any(tnz != 0) ? 1 : 0;
    if (lane == 0) snz[w] = wnz;
    __syncthreads();
    if (t == 0) flags[blockIdx.x] = snz[0] | snz[1] | snz[2] | snz[3];
}

// ---------------------------------------------------------------------------
// Legacy fp32 fallback GEMM (only if ws is tiny). SK=1 P layout.
__global__ __launch_bounds__(256) void legacy_gemm_kernel(
    const float* __restrict__ x, const float* __restrict__ x0,
    const float* __restrict__ W1, float* __restrict__ P,
    const int* __restrict__ flags) {
    const int ct = blockIdx.x, z = blockIdx.z, t = threadIdx.x;
    if (z == 1 && !read_nz(flags)) return;
    const int cg = t & 7, rg = t >> 3;
    const int r0 = rg * 4, cc = ct * 64 + cg * 8;
    float acc[4][8];
#pragma unroll
    for (int i = 0; i < 4; ++i)
#pragma unroll
        for (int n = 0; n < 8; ++n) acc[i][n] = 0.f;
    const float* __restrict__ X = z ? x0 : x;
    for (int k = 0; k < FF; k += 4) {
        float xr[4][4];
#pragma unroll
        for (int i = 0; i < 4; ++i) {
            float4 v = *(const float4*)(X + (size_t)(r0 + i) * FF + k);
            xr[i][0] = v.x; xr[i][1] = v.y; xr[i][2] = v.z; xr[i][3] = v.w;
        }
        float wr[4][8];
#pragma unroll
        for (int j = 0; j < 4; ++j) {
            float4 a = *(const float4*)(W1 + (size_t)(k + j) * HH + cc);
            float4 b = *(const float4*)(W1 + (size_t)(k + j) * HH + cc + 4);
            wr[j][0] = a.x; wr[j][1] = a.y; wr[j][2] = a.z; wr[j][3] = a.w;
            wr[j][4] = b.x; wr[j][5] = b.y; wr[j][6] = b.z; wr[j][7] = b.w;
        }
#pragma unroll
        for (int j = 0; j < 4; ++j)
#pragma unroll
            for (int i = 0; i < 4; ++i)
#pragma unroll
                for (int n = 0; n < 8; ++n)
                    acc[i][n] = fmaf(xr[i][j], wr[j][n], acc[i][n]);
    }
    float* Pp = P + (size_t)z * BH;
#pragma unroll
    for (int i = 0; i < 4; ++i) {
        float4 o0, o1;
        o0.x = acc[i][0]; o0.y = acc[i][1]; o0.z = acc[i][2]; o0.w = acc[i][3];
        o1.x = acc[i][4]; o1.y = acc[i][5]; o1.z = acc[i][6]; o1.w = acc[i][7];
        *(float4*)(Pp + (size_t)(r0 + i) * HH + cc) = o0;
        *(float4*)(Pp + (size_t)(r0 + i) * HH + cc + 4) = o1;
    }
}

// ---------------------------------------------------------------------------
// Fused: wide fixed-order split-K reduction + bisection + output write.
// One block of 1024 threads per sample; each thread owns 2 h-columns (float2).
// When x0 == 0: relu(c*u) = c*relu(u) -> f(c) = c*S - tau, scalar loop.
__global__ __launch_bounds__(1024) void bisect_write_kernel(
    const float* __restrict__ P, const float* __restrict__ w2,
    const float* __restrict__ x, const float* __restrict__ x0,
    const int* __restrict__ flags, float* __restrict__ out, int SK) {
    const int b = blockIdx.x;
    const int t = threadIdx.x;
    const int w = t >> 6;
    const int lane = t & 63;
    __shared__ float red[16];
    const bool nz = read_nz(flags);

    // Fixed-order split-K reduce of u1 (2 columns per thread, coalesced).
    const float2* P1 = (const float2*)(P + (size_t)b * HH) + t;
    float2 u1 = {0.f, 0.f};
    for (int kc = 0; kc < SK; ++kc) {           // fixed order: deterministic
        const float2 v = P1[(size_t)kc * (BH / 2)];
        u1.x += v.x; u1.y += v.y;
    }
    const float2 wv = ((const float2*)w2)[t];

    auto blockReduce = [&](float v) -> float {
#pragma unroll
        for (int off = 32; off > 0; off >>= 1) v += __shfl_xor(v, off);
        if (lane == 0) red[w] = v;
        __syncthreads();
        float s = 0.f;
#pragma unroll
        for (int i = 0; i < 16; ++i) s += red[i];  // fixed order, uniform
        __syncthreads();
        return s;
    };

    float c = 1.f;
    bool done = false;
    if (!nz) {
        // Linear path: f(c) = c*S - tau.
        float p = fmaf(fmaxf(u1.x, 0.f), wv.x, fmaxf(u1.y, 0.f) * wv.y);
        const float S = blockReduce(p);
        const float f1 = S - TAU_F;
        const bool inside = (f1 <= 0.f);
        float a = 0.f, bh = 1.f;
        done = inside;
        for (int it = 0; it < 30; ++it) {
            const float cm = 0.5f * (a + bh);
            const float v = cm * S - TAU_F;
            const bool upd  = !done;
            const bool hit  = upd && (v >= -THR_F) && (v < 0.f);
            const bool go_a = upd && (v < 0.f) && !hit;
            const bool go_b = upd && (v >= 0.f);
            a  = go_a ? cm : a;
            bh = go_b ? cm : bh;
            c  = upd  ? cm : c;
            done = done || hit;
        }
        c = inside ? 1.f : c;
    } else {
        const float2* P0 = (const float2*)(P + (size_t)(SK * BH) + (size_t)b * HH) + t;
        float2 u0 = {0.f, 0.f};
        for (int kc = 0; kc < SK; ++kc) {
            const float2 v = P0[(size_t)kc * (BH / 2)];
            u0.x += v.x; u0.y += v.y;
        }
        const float2 dd = {u1.x - u0.x, u1.y - u0.y};
        auto feval = [&](float cc) -> float {
            float p = fmaf(fmaxf(fmaf(cc, dd.x, u0.x), 0.f), wv.x,
                           fmaxf(fmaf(cc, dd.y, u0.y), 0.f) * wv.y);
            return blockReduce(p) - TAU_F;
        };
        const float f1 = feval(1.f);
        const bool inside = (f1 <= 0.f);
        float a = 0.f, bh = 1.f;
        done = inside;
        for (int it = 0; it < 30; ++it) {
            const float cm = 0.5f * (a + bh);
            const float v = feval(cm);
            const bool upd  = !done;
            const bool hit  = upd && (v >= -THR_F) && (v < 0.f);
            const bool go_a = upd && (v < 0.f) && !hit;
            const bool go_b = upd && (v >= 0.f);
            a  = go_a ? cm : a;
            bh = go_b ? cm : bh;
            c  = upd  ? cm : c;
            done = done || hit;
        }
        c = inside ? 1.f : c;
    }

    // Write output row b (uniform branches across block). FF/4/1024 = 3 f4/thr.
    const float nanv = __int_as_float(0x7fc00000);
    const float4* xr  = (const float4*)(x  + (size_t)b * FF);
    const float4* x0r = (const float4*)(x0 + (size_t)b * FF);
    float4* orow = (float4*)(out + (size_t)b * FF);
    if (!done) {
        float4 o; o.x = o.y = o.z = o.w = nanv;
#pragma unroll
        for (int k2 = 0; k2 < 3; ++k2) orow[t + 1024 * k2] = o;
    } else if (!nz) {
#pragma unroll
        for (int k2 = 0; k2 < 3; ++k2) {
            const int i = t + 1024 * k2;
            float4 xv = xr[i], o;
            o.x = c * xv.x; o.y = c * xv.y; o.z = c * xv.z; o.w = c * xv.w;
            orow[i] = o;
        }
    } else {
#pragma unroll
        for (int k2 = 0; k2 < 3; ++k2) {
            const int i = t + 1024 * k2;
            float4 xv = xr[i], zv = x0r[i], o;
            o.x = fmaf(c, xv.x - zv.x, zv.x);
            o.y = fmaf(c, xv.y - zv.y, zv.y);
            o.z = fmaf(c, xv.z - zv.z, zv.z);
            o.w = fmaf(c, xv.w - zv.w, zv.w);
            orow[i] = o;
        }
    }
}

// ---------------------------------------------------------------------------
extern "C" void kernel_launch(void* const* d_in, const int* in_sizes, int n_in,
                              void* d_out, int out_size, void* d_ws, size_t ws_size,
                              hipStream_t stream) {
    const float* x0 = (const float*)d_in[0];
    const float* x  = (const float*)d_in[1];
    const float* W1 = (const float*)d_in[2];
    const float* w2 = (const float*)d_in[3];
    float* out = (float*)d_out;
    char* ws = (char*)d_ws;

    // ws layout: Ah | Al | flags[192] (pad 1024) | P[2*SK][B][H]
    const size_t szA   = (size_t)2 * NKG * BB * 8 * sizeof(unsigned short); // 6291456
    const size_t offAl = szA;
    const size_t offFl = 2 * szA;
    const size_t offP  = offFl + 1024;

    int SK = 0;
    const int cand[5] = {16, 8, 4, 2, 1};
    for (int i = 0; i < 5; ++i) {
        const size_t need = offP + (size_t)2 * cand[i] * BH * sizeof(float);
        if (ws_size >= need) { SK = cand[i]; break; }
    }

    if (SK > 0) {
        unsigned short* Ah = (unsigned short*)ws;
        unsigned short* Al = (unsigned short*)(ws + offAl);
        int*   flags = (int*)(ws + offFl);
        float* P     = (float*)(ws + offP);
        const int KC = FF / SK, NIT = KC / 32;

        presplit_kernel<<<dim3(NKG / 8, 2), 256, 0, stream>>>(x, x0, Ah, Al, flags);
        mfma_gemm_kernel<<<dim3(32 * SK, 2), 256, 0, stream>>>(Ah, Al, W1, P, flags, SK, KC, NIT);
        bisect_write_kernel<<<BB, 1024, 0, stream>>>(P, w2, x, x0, flags, out, SK);
    } else {
        // Low-memory fallback: fp32 VALU GEMM, SK=1 layout.
        float* P     = (float*)ws;
        int*   flags = (int*)(ws + (size_t)2 * BH * sizeof(float));
        zflags_kernel<<<NFLAGS, 256, 0, stream>>>((const float4*)x0, flags);
        legacy_gemm_kernel<<<dim3(32, 1, 2), 256, 0, stream>>>(x, x0, W1, P, flags);
        bisect_write_kernel<<<BB, 1024, 0, stream>>>(P, w2, x, x0, flags, out, 1);
    }
}